// Round 18
// baseline (324.629 us; speedup 1.0000x reference)
//
#include <hip/hip_runtime.h>
#include <math.h>

// EGCL_Multi on MFMA. R16/R17 base, rebalanced wave tiling: 8 waves =
// 2 row-groups(32) x 4 col-groups(64) -> per-GEMM ds_read_b128 drops
// 576 -> 384 (B-frag redundancy 2x not 4x). Single-buffer staging (dbuf
// regressed twice). Coalesced k_pre. N=512, NH=8, HD=128, M=256.
#define N_NODES 512
#define NH 8
#define HD 128
#define M 256
#define PITCH 264        // LDS activation row pitch in bf16 (528B)
#define JTILE 64         // edges (j) per block = 2 row-groups x 32

typedef __bf16 v8bf __attribute__((ext_vector_type(8)));
typedef float f32x4 __attribute__((ext_vector_type(4)));

__device__ __forceinline__ float silu_f(float v) {
  return v * __builtin_amdgcn_rcpf(1.f + __expf(-v));
}
__device__ __forceinline__ float sigmoid_f(float v) {
  return __builtin_amdgcn_rcpf(1.f + __expf(-v));
}
__device__ __forceinline__ unsigned short f2bf(float f) {   // RNE (prep only)
  unsigned u = __float_as_uint(f);
  u += 0x7fffu + ((u >> 16) & 1u);
  return (unsigned short)(u >> 16);
}
__device__ __forceinline__ unsigned short f2bf_hi(float f) { // cheap half-up
  return (unsigned short)((__float_as_uint(f) + 0x8000u) >> 16);
}
__device__ __forceinline__ float bf2f(unsigned short s) {
  return __uint_as_float(((unsigned)s) << 16);
}

// async global->LDS, 16B/lane; LDS dest = wave-uniform base + lane*16.
__device__ __forceinline__ void gl2lds16(const unsigned short* g, unsigned short* l) {
  __builtin_amdgcn_global_load_lds(
      (const __attribute__((address_space(1))) unsigned int*)g,
      (__attribute__((address_space(3))) unsigned int*)l, 16, 0, 0);
}

// ---------------------------------------------------------------------------
// Fused prep (blocks 0..815, coalesced source reads) + P/Q & zeroing (816..).
// Frag layout: frag[((kt*16+nt)*64+lane)*8+j] = W[kt*32+(lane>>4)*8+j][nt*16+(lane&15)]
// We1 @0, Wx0 @65536, Wx1 @131072, Wxo(256x8 pad16) @196608,
// We0[0:8] (K=8 pad 32, 16 nt tiles) @200704 (8192 shorts).
// ---------------------------------------------------------------------------
__global__ __launch_bounds__(256) void k_pre(
    const float* __restrict__ x, const float* __restrict__ h,
    const float* __restrict__ We0, const float* __restrict__ be0,
    const float* __restrict__ We1, const float* __restrict__ Wx0,
    const float* __restrict__ Wx1, const float* __restrict__ Wxo,
    unsigned short* __restrict__ wsB,
    float* __restrict__ P, float* __restrict__ Q,
    float* __restrict__ mi, float* __restrict__ shift)
{
  const int t = threadIdx.x;
  if (blockIdx.x < 816) {
    const int gid = blockIdx.x * 256 + t;
    if (gid >= 208896) return;
    float val;
    int dst;
    if (gid < 196608) {                      // We1/Wx0/Wx1: e = k*256+n
      const int layer = gid >> 16, e = gid & 65535;
      const int k = e >> 8, n = e & 255;
      const float* W = (layer == 0) ? We1 : (layer == 1) ? Wx0 : Wx1;
      val = W[e];
      const int kt = k >> 5, w = k & 31, quad = w >> 3, j = w & 7;
      const int nt = n >> 4, lnib = n & 15;
      dst = layer * 65536 + ((kt * 16 + nt) * 64 + quad * 16 + lnib) * 8 + j;
    } else if (gid < 198656) {               // Wxo valid
      const int e = gid - 196608;
      val = Wxo[e];
      const int k = e >> 3, col = e & 7;
      const int kt = k >> 5, w = k & 31, quad = w >> 3, j = w & 7;
      dst = 196608 + (kt * 64 + quad * 16 + col) * 8 + j;
    } else if (gid < 200704) {               // Wxo pad
      const int e = gid - 198656;
      val = 0.f;
      const int k = e >> 3, col = e & 7;
      const int kt = k >> 5, w = k & 31, quad = w >> 3, j = w & 7;
      dst = 196608 + (kt * 64 + quad * 16 + col + 8) * 8 + j;
    } else if (gid < 202752) {               // We0[0:8] valid
      const int e = gid - 200704;
      val = We0[e];
      const int j = e >> 8, n = e & 255, nt = n >> 4, lnib = n & 15;
      dst = 200704 + (nt * 64 + lnib) * 8 + j;
    } else {                                 // We0 frag zero rows
      const int e = gid - 202752;
      val = 0.f;
      const int q = 1 + (e >> 11), rem = e & 2047;
      const int j = rem & 7, lnib = (rem >> 3) & 15, nt = rem >> 7;
      dst = 200704 + (nt * 64 + q * 16 + lnib) * 8 + j;
    }
    wsB[dst] = f2bf(val);
    return;
  }
  // ---- P/Q branch ----
  const int i = blockIdx.x - 816;
  __shared__ float s_x[24];
  __shared__ float s_hc[192];
  mi[i * M + t] = 0.f;
  if (t < 24) { shift[i * 24 + t] = 0.f; s_x[t] = x[i * 24 + t]; }
  __syncthreads();
  if (t < HD) {
    s_hc[t] = h[i * HD + t];
  } else if (t < 192) {
    const int p = t - HD, a = p >> 3, b = p & 7;
    float s = 0.f;
#pragma unroll
    for (int d = 0; d < 3; ++d) {
      const float dx = s_x[a * 3 + d] - s_x[b * 3 + d];
      s = fmaf(dx, dx, s);
    }
    s_hc[t] = s;
  }
  __syncthreads();
  float p = 0.f, q = 0.f;
  for (int k = 0; k < 192; ++k) {
    const float hv = s_hc[k];
    p = fmaf(hv, We0[(8 + k) * M + t], p);
    q = fmaf(hv, We0[(200 + k) * M + t], q);
  }
  P[i * M + t] = p;
  Q[i * M + t] = q + be0[t];                 // be0 folded
}

// ---------------------------------------------------------------------------
// Fused edge pipeline. Block = (i, 64-j tile), 512 threads = 8 waves.
// Wave w: row-group rg = w>>2 (rows [32rg,32rg+32)), col-group cg = w&3
// (cols [64cg, 64cg+64)). acc[2][4] = 32 AGPRs.
// ---------------------------------------------------------------------------
__global__ __launch_bounds__(512, 4) void k_edge(
    const float* __restrict__ x,
    const float* __restrict__ P, const float* __restrict__ Q,
    const float* __restrict__ be1,
    const float* __restrict__ Winf, const float* __restrict__ binf,
    const float* __restrict__ bx0, const float* __restrict__ bx1,
    const float* __restrict__ bxo,
    const unsigned short* __restrict__ wsB,
    float* __restrict__ mi_acc, float* __restrict__ shift_acc)
{
  const int i  = blockIdx.x;
  const int j0 = blockIdx.y * JTILE;
  const int t  = threadIdx.x;
  const int lane = t & 63, wave = t >> 6;
  const int lnib = lane & 15, quad = lane >> 4;
  const int rg = wave >> 2, cg = wave & 3;
  const int r0 = rg * 32;          // block-local row base (32 rows)
  const int jw = j0 + r0;
  const int cb = cg * 64;          // column base (64 cols)

  __shared__ __align__(16) unsigned short a_act[JTILE * PITCH];   // 33 KB
  __shared__ __align__(16) unsigned short B_buf[8192];            // 16 KB
  __shared__ __align__(16) float s_sqn[JTILE][8];                 // 2 KB
  __shared__ __align__(16) unsigned short s_sqnb[JTILE][8];       // 1 KB
  __shared__ float s_red[JTILE][4];                               // 1 KB
  __shared__ float s_e[JTILE];                                    // 256 B

  // one kt slice of B: wave stages 1024 shorts (2KB)
  auto stage = [&](const unsigned short* __restrict__ Bg, int kt) {
    const unsigned short* src = Bg + kt * 8192 + wave * 1024 + lane * 8;
    unsigned short* dst = &B_buf[wave * 1024];   // wave-uniform base
    gl2lds16(src,       dst);
    gl2lds16(src + 512, dst + 512);
  };

  // ---- sqn for this wave's 32 rows (row-group waves duplicate - benign) ----
#pragma unroll
  for (int kk = 0; kk < 4; ++kk) {
    const int idx = kk * 64 + lane;          // 0..255 = 32 rows x 8 heads
    const int r = idx >> 3, hh = idx & 7;
    const int j = jw + r;
    float s = 0.f;
#pragma unroll
    for (int d = 0; d < 3; ++d) {
      const float dx = x[j * 24 + hh * 3 + d] - x[i * 24 + hh * 3 + d];
      s = fmaf(dx, dx, s);
    }
    s_sqn[r0 + r][hh] = s;
    s_sqnb[r0 + r][hh] = f2bf(s);
  }

  const float binf0 = binf[0];

  f32x4 acc[2][4];                           // 32 floats -> AGPRs

  // ---- stage 0 via MFMA: acc init = P[j-row][col]; A = sqn bf16 (k>=8
  //      garbage, B frag rows zero); epilogue adds Q'[i] + silu -> a_act ----
  {
#pragma unroll
    for (int rf = 0; rf < 2; ++rf)
#pragma unroll
      for (int nt = 0; nt < 4; ++nt)
#pragma unroll
        for (int reg = 0; reg < 4; ++reg)
          acc[rf][nt][reg] =
              P[(jw + rf * 16 + quad * 4 + reg) * M + cb + nt * 16 + lnib];
    const v8bf aS0 = *(const v8bf*)&s_sqnb[r0 + lnib][0];
    const v8bf aS1 = *(const v8bf*)&s_sqnb[r0 + 16 + lnib][0];
    const unsigned short* B0 = wsB + 200704;
#pragma unroll
    for (int nt = 0; nt < 4; ++nt) {
      const v8bf bv = *(const v8bf*)&B0[((cg * 4 + nt) * 64 + lane) * 8];
      acc[0][nt] = __builtin_amdgcn_mfma_f32_16x16x32_bf16(aS0, bv, acc[0][nt], 0, 0, 0);
      acc[1][nt] = __builtin_amdgcn_mfma_f32_16x16x32_bf16(aS1, bv, acc[1][nt], 0, 0, 0);
    }
#pragma unroll
    for (int rf = 0; rf < 2; ++rf)
#pragma unroll
      for (int nt = 0; nt < 4; ++nt) {
        const float qv = Q[i * M + cb + nt * 16 + lnib];
#pragma unroll
        for (int reg = 0; reg < 4; ++reg) {
          const int row = r0 + rf * 16 + quad * 4 + reg;
          a_act[row * PITCH + cb + nt * 16 + lnib] =
              f2bf_hi(silu_f(acc[rf][nt][reg] + qv));
        }
      }
  }

  // GEMM over this wave's 32 rows x 64 cols; B staged per-kt through LDS.
  // Trailing barrier: epilogues write rows other waves read as A.
  auto run_gemm = [&](const unsigned short* __restrict__ Bg) {
#pragma unroll
    for (int kt = 0; kt < 8; ++kt) {
      __syncthreads();                       // prior slice reads done
      stage(Bg, kt);
      __syncthreads();                       // staging complete
      const v8bf a0 = *(const v8bf*)&a_act[(r0 + lnib) * PITCH + kt * 32 + quad * 8];
      const v8bf a1 = *(const v8bf*)&a_act[(r0 + 16 + lnib) * PITCH + kt * 32 + quad * 8];
#pragma unroll
      for (int nt = 0; nt < 4; ++nt) {
        const v8bf bv = *(const v8bf*)&B_buf[(cg * 4 + nt) * 512 + lane * 8];
        acc[0][nt] = __builtin_amdgcn_mfma_f32_16x16x32_bf16(a0, bv, acc[0][nt], 0, 0, 0);
        acc[1][nt] = __builtin_amdgcn_mfma_f32_16x16x32_bf16(a1, bv, acc[1][nt], 0, 0, 0);
      }
    }
    __syncthreads();                         // all A-reads done -> epilogue safe
  };

  // ===== GEMM1: m = silu(a1 @ We1 + be1), diag mask, gate =====
#pragma unroll
  for (int rf = 0; rf < 2; ++rf)
#pragma unroll
    for (int nt = 0; nt < 4; ++nt) {
      const float b = be1[cb + nt * 16 + lnib];
      acc[rf][nt] = (f32x4){b, b, b, b};
    }
  run_gemm(wsB);
  {
    float ge[2][4] = {{0.f, 0.f, 0.f, 0.f}, {0.f, 0.f, 0.f, 0.f}};
#pragma unroll
    for (int rf = 0; rf < 2; ++rf)
#pragma unroll
      for (int nt = 0; nt < 4; ++nt) {
        const float wfv = Winf[cb + nt * 16 + lnib];
#pragma unroll
        for (int reg = 0; reg < 4; ++reg) {
          float v = silu_f(acc[rf][nt][reg]);
          const int row = r0 + rf * 16 + quad * 4 + reg;
          if (j0 + row == i) v = 0.f;
          a_act[row * PITCH + cb + nt * 16 + lnib] = f2bf_hi(v);
          ge[rf][reg] = fmaf(v, wfv, ge[rf][reg]);
        }
      }
#pragma unroll
    for (int rf = 0; rf < 2; ++rf)
#pragma unroll
      for (int reg = 0; reg < 4; ++reg) {
        float g = ge[rf][reg];
        g += __shfl_xor(g, 1);
        g += __shfl_xor(g, 2);
        g += __shfl_xor(g, 4);
        g += __shfl_xor(g, 8);
        if (lnib == 0) s_red[r0 + rf * 16 + quad * 4 + reg][cg] = g;
      }
  }
  __syncthreads();                           // m writes + gate partials visible
  if (t < JTILE)
    s_e[t] = sigmoid_f(s_red[t][0] + s_red[t][1] + s_red[t][2] + s_red[t][3] + binf0);
  __syncthreads();

  // ===== mi: re-read own (32 rows x 64 cols) of m, scaled by e[row] =====
  {
    const int ch = cb + (lane & 31) * 2;     // 2 channels per lane
    const int rh = (lane >> 5) * 16;         // row half
    float m0 = 0.f, m1 = 0.f;
#pragma unroll
    for (int r = 0; r < 16; ++r) {
      const int row = r0 + rh + r;
      const unsigned mv = *(const unsigned*)&a_act[row * PITCH + ch];
      const float ev = s_e[row];
      m0 = fmaf(bf2f((unsigned short)(mv & 0xffffu)), ev, m0);
      m1 = fmaf(bf2f((unsigned short)(mv >> 16)), ev, m1);
    }
    m0 += __shfl_xor(m0, 32);                // combine row halves
    m1 += __shfl_xor(m1, 32);
    if (lane < 32) {
      atomicAdd(&mi_acc[i * M + ch + 0], m0);
      atomicAdd(&mi_acc[i * M + ch + 1], m1);
    }
  }

  // ===== GEMM2: a2 = silu(m @ Wx0 + bx0) =====
#pragma unroll
  for (int rf = 0; rf < 2; ++rf)
#pragma unroll
    for (int nt = 0; nt < 4; ++nt) {
      const float b = bx0[cb + nt * 16 + lnib];
      acc[rf][nt] = (f32x4){b, b, b, b};
    }
  run_gemm(wsB + 65536);
#pragma unroll
  for (int rf = 0; rf < 2; ++rf)
#pragma unroll
    for (int nt = 0; nt < 4; ++nt)
#pragma unroll
      for (int reg = 0; reg < 4; ++reg) {
        const int row = r0 + rf * 16 + quad * 4 + reg;
        a_act[row * PITCH + cb + nt * 16 + lnib] = f2bf_hi(silu_f(acc[rf][nt][reg]));
      }

  // ===== GEMM3: a3 = silu(a2 @ Wx1 + bx1) =====
#pragma unroll
  for (int rf = 0; rf < 2; ++rf)
#pragma unroll
    for (int nt = 0; nt < 4; ++nt) {
      const float b = bx1[cb + nt * 16 + lnib];
      acc[rf][nt] = (f32x4){b, b, b, b};
    }
  run_gemm(wsB + 131072);
#pragma unroll
  for (int rf = 0; rf < 2; ++rf)
#pragma unroll
    for (int nt = 0; nt < 4; ++nt)
#pragma unroll
      for (int reg = 0; reg < 4; ++reg) {
        const int row = r0 + rf * 16 + quad * 4 + reg;
        a_act[row * PITCH + cb + nt * 16 + lnib] = f2bf_hi(silu_f(acc[rf][nt][reg]));
      }
  __syncthreads();                           // a3 complete (GEMM4 reads all cols)

  // ===== GEMM4 + shift: cg==0 waves (2 waves, 32 rows each) =====
  if (cg == 0) {
    f32x4 px[2];
    {
      const float b = (lnib < 8) ? bxo[lnib] : 0.f;
      px[0] = (f32x4){b, b, b, b};
      px[1] = (f32x4){b, b, b, b};
      const unsigned short* B = wsB + 196608;
#pragma unroll
      for (int kt = 0; kt < 8; ++kt) {
        const v8bf a0 = *(const v8bf*)&a_act[(r0 + lnib) * PITCH + kt * 32 + quad * 8];
        const v8bf a1 = *(const v8bf*)&a_act[(r0 + 16 + lnib) * PITCH + kt * 32 + quad * 8];
        const v8bf bv = *(const v8bf*)&B[(kt * 64 + lane) * 8];
        px[0] = __builtin_amdgcn_mfma_f32_16x16x32_bf16(a0, bv, px[0], 0, 0, 0);
        px[1] = __builtin_amdgcn_mfma_f32_16x16x32_bf16(a1, bv, px[1], 0, 0, 0);
      }
    }
    const int hh = lnib & 7;   // lanes lnib>=8 hold zero px (padded B cols)
    const float xi0 = x[i * 24 + hh * 3 + 0];
    const float xi1 = x[i * 24 + hh * 3 + 1];
    const float xi2 = x[i * 24 + hh * 3 + 2];
    float p0 = 0.f, p1 = 0.f, p2 = 0.f;
#pragma unroll
    for (int rf = 0; rf < 2; ++rf)
#pragma unroll
      for (int reg = 0; reg < 4; ++reg) {
        const int row = r0 + rf * 16 + quad * 4 + reg;
        const int jg = j0 + row;
        if (jg != i) {
          const float pxv = px[rf][reg];
          const float sq  = s_sqn[row][hh];
          const float f   = pxv * __builtin_amdgcn_rcpf(sqrtf(sq + 1e-8f) + 1.f);
          p0 = fmaf(x[jg * 24 + hh * 3 + 0] - xi0, f, p0);
          p1 = fmaf(x[jg * 24 + hh * 3 + 1] - xi1, f, p1);
          p2 = fmaf(x[jg * 24 + hh * 3 + 2] - xi2, f, p2);
        }
      }
    p0 += __shfl_xor(p0, 16); p0 += __shfl_xor(p0, 32);
    p1 += __shfl_xor(p1, 16); p1 += __shfl_xor(p1, 32);
    p2 += __shfl_xor(p2, 16); p2 += __shfl_xor(p2, 32);
    if (lane < 8) {
      atomicAdd(&shift_acc[i * 24 + hh * 3 + 0], p0);
      atomicAdd(&shift_acc[i * 24 + hh * 3 + 1], p1);
      atomicAdd(&shift_acc[i * 24 + hh * 3 + 2], p2);
    }
  }
}

// ---------------------------------------------------------------------------
// h-output (phi_h MLP + residual) with x-output folded in (threads t<24).
// ---------------------------------------------------------------------------
__global__ __launch_bounds__(256) void k_hout(
    const float* __restrict__ x, const float* __restrict__ shift,
    const float* __restrict__ h, const float* __restrict__ mi,
    const float* __restrict__ Wh0, const float* __restrict__ bh0,
    const float* __restrict__ Wh1, const float* __restrict__ bh1,
    const float* __restrict__ Who, const float* __restrict__ bho,
    float* __restrict__ out_x, float* __restrict__ out_h)
{
  const int i = blockIdx.x, t = threadIdx.x;
  __shared__ float s_in[M + HD];
  __shared__ float s_b[M];
  if (t < 24) out_x[i * 24 + t] = x[i * 24 + t] + shift[i * 24 + t] * (1.f / 511.f);
  s_in[t] = mi[i * M + t];
  if (t < HD) s_in[M + t] = h[i * HD + t];
  __syncthreads();
  float acc = bh0[t];
  for (int k = 0; k < M + HD; ++k) acc = fmaf(s_in[k], Wh0[k * M + t], acc);
  s_b[t] = silu_f(acc);
  __syncthreads();
  float acc2 = bh1[t];
  for (int k = 0; k < M; ++k) acc2 = fmaf(s_b[k], Wh1[k * M + t], acc2);
  const float a1v = silu_f(acc2);
  __syncthreads();
  s_in[t] = a1v;
  __syncthreads();
  if (t < HD) {
    float o = bho[t];
    for (int k = 0; k < M; ++k) o = fmaf(s_in[k], Who[k * HD + t], o);
    out_h[i * HD + t] = h[i * HD + t] + o;
  }
}

// ---------------------------------------------------------------------------
extern "C" void kernel_launch(void* const* d_in, const int* in_sizes, int n_in,
                              void* d_out, int out_size, void* d_ws, size_t ws_size,
                              hipStream_t stream)
{
  const float* x    = (const float*)d_in[0];
  const float* h    = (const float*)d_in[1];
  const float* We0  = (const float*)d_in[2];
  const float* be0  = (const float*)d_in[3];
  const float* We1  = (const float*)d_in[4];
  const float* be1  = (const float*)d_in[5];
  const float* Winf = (const float*)d_in[6];
  const float* binf = (const float*)d_in[7];
  const float* Wx0  = (const float*)d_in[8];
  const float* bx0  = (const float*)d_in[9];
  const float* Wx1  = (const float*)d_in[10];
  const float* bx1  = (const float*)d_in[11];
  const float* Wxo  = (const float*)d_in[12];
  const float* bxo  = (const float*)d_in[13];
  const float* Wh0  = (const float*)d_in[14];
  const float* bh0  = (const float*)d_in[15];
  const float* Wh1  = (const float*)d_in[16];
  const float* bh1  = (const float*)d_in[17];
  const float* Who  = (const float*)d_in[18];
  const float* bho  = (const float*)d_in[19];

  float* out_x = (float*)d_out;                 // [512,8,3]
  float* out_h = out_x + N_NODES * NH * 3;      // [512,128]

  // ws layout (float units): mi[131072] | shift[12288] | P[131072] | Q[131072] | wsB(bf16)
  float* ws    = (float*)d_ws;
  float* mi    = ws;
  float* shift = ws + 131072;
  float* P     = ws + 143360;
  float* Q     = ws + 274432;
  unsigned short* wsB = (unsigned short*)(ws + 405504);

  k_pre<<<816 + N_NODES, 256, 0, stream>>>(
      x, h, We0, be0, We1, Wx0, Wx1, Wxo, wsB, P, Q, mi, shift);
  k_edge<<<dim3(N_NODES, N_NODES / JTILE), 512, 0, stream>>>(
      x, P, Q, be1, Winf, binf, bx0, bx1, bxo, wsB, mi, shift);
  k_hout<<<N_NODES, 256, 0, stream>>>(
      x, shift, h, mi, Wh0, bh0, Wh1, bh1, Who, bho, out_x, out_h);
}

// Round 19
// 316.888 us; speedup vs baseline: 1.0244x; 1.0244x over previous
//
#include <hip/hip_runtime.h>
#include <math.h>

// EGCL_Multi on MFMA. Best-of recombination: R13's edge kernel (222 us,
// 256-thr, 4 waves x 16 rows, single 16KB B_buf, rcp-silu, stage-0 MFMA)
// + R17's coalesced weight-prep / fused P/Q / fused hout+xout.
// N=512, NH=8, HD=128, M=256.
#define N_NODES 512
#define NH 8
#define HD 128
#define M 256
#define PITCH 264        // LDS activation row pitch in bf16 (528B)
#define JTILE 64         // edges (j) per block = 4 waves x 16
#define RPW 16           // rows per wave

typedef __bf16 v8bf __attribute__((ext_vector_type(8)));
typedef float f32x4 __attribute__((ext_vector_type(4)));
typedef unsigned short us4v __attribute__((ext_vector_type(4)));

__device__ __forceinline__ float silu_f(float v) {
  return v * __builtin_amdgcn_rcpf(1.f + __expf(-v));
}
__device__ __forceinline__ float sigmoid_f(float v) {
  return __builtin_amdgcn_rcpf(1.f + __expf(-v));
}
__device__ __forceinline__ unsigned short f2bf(float f) {   // RNE (prep only)
  unsigned u = __float_as_uint(f);
  u += 0x7fffu + ((u >> 16) & 1u);
  return (unsigned short)(u >> 16);
}
__device__ __forceinline__ unsigned short f2bf_hi(float f) { // cheap half-up
  return (unsigned short)((__float_as_uint(f) + 0x8000u) >> 16);
}
__device__ __forceinline__ float bf2f(unsigned short s) {
  return __uint_as_float(((unsigned)s) << 16);
}

// async global->LDS, 16B/lane; LDS dest = wave-uniform base + lane*16.
__device__ __forceinline__ void gl2lds16(const unsigned short* g, unsigned short* l) {
  __builtin_amdgcn_global_load_lds(
      (const __attribute__((address_space(1))) unsigned int*)g,
      (__attribute__((address_space(3))) unsigned int*)l, 16, 0, 0);
}

// ---------------------------------------------------------------------------
// Fused prep (blocks 0..815, coalesced source reads) + P/Q & zeroing (816..).
// Frag layout: frag[((kt*16+nt)*64+lane)*8+j] = W[kt*32+(lane>>4)*8+j][nt*16+(lane&15)]
// We1 @0, Wx0 @65536, Wx1 @131072, Wxo(256x8 pad16) @196608,
// We0[0:8] (K=8 pad 32, 16 nt tiles) @200704 (8192 shorts).
// ---------------------------------------------------------------------------
__global__ __launch_bounds__(256) void k_pre(
    const float* __restrict__ x, const float* __restrict__ h,
    const float* __restrict__ We0, const float* __restrict__ be0,
    const float* __restrict__ We1, const float* __restrict__ Wx0,
    const float* __restrict__ Wx1, const float* __restrict__ Wxo,
    unsigned short* __restrict__ wsB,
    float* __restrict__ P, float* __restrict__ Q,
    float* __restrict__ mi, float* __restrict__ shift)
{
  const int t = threadIdx.x;
  if (blockIdx.x < 816) {
    const int gid = blockIdx.x * 256 + t;
    if (gid >= 208896) return;
    float val;
    int dst;
    if (gid < 196608) {                      // We1/Wx0/Wx1: e = k*256+n
      const int layer = gid >> 16, e = gid & 65535;
      const int k = e >> 8, n = e & 255;
      const float* W = (layer == 0) ? We1 : (layer == 1) ? Wx0 : Wx1;
      val = W[e];
      const int kt = k >> 5, w = k & 31, quad = w >> 3, j = w & 7;
      const int nt = n >> 4, lnib = n & 15;
      dst = layer * 65536 + ((kt * 16 + nt) * 64 + quad * 16 + lnib) * 8 + j;
    } else if (gid < 198656) {               // Wxo valid
      const int e = gid - 196608;
      val = Wxo[e];
      const int k = e >> 3, col = e & 7;
      const int kt = k >> 5, w = k & 31, quad = w >> 3, j = w & 7;
      dst = 196608 + (kt * 64 + quad * 16 + col) * 8 + j;
    } else if (gid < 200704) {               // Wxo pad
      const int e = gid - 198656;
      val = 0.f;
      const int k = e >> 3, col = e & 7;
      const int kt = k >> 5, w = k & 31, quad = w >> 3, j = w & 7;
      dst = 196608 + (kt * 64 + quad * 16 + col + 8) * 8 + j;
    } else if (gid < 202752) {               // We0[0:8] valid
      const int e = gid - 200704;
      val = We0[e];
      const int j = e >> 8, n = e & 255, nt = n >> 4, lnib = n & 15;
      dst = 200704 + (nt * 64 + lnib) * 8 + j;
    } else {                                 // We0 frag zero rows
      const int e = gid - 202752;
      val = 0.f;
      const int q = 1 + (e >> 11), rem = e & 2047;
      const int j = rem & 7, lnib = (rem >> 3) & 15, nt = rem >> 7;
      dst = 200704 + (nt * 64 + q * 16 + lnib) * 8 + j;
    }
    wsB[dst] = f2bf(val);
    return;
  }
  // ---- P/Q branch ----
  const int i = blockIdx.x - 816;
  __shared__ float s_x[24];
  __shared__ float s_hc[192];
  mi[i * M + t] = 0.f;                       // zeroing replaces memset
  if (t < 24) { shift[i * 24 + t] = 0.f; s_x[t] = x[i * 24 + t]; }
  __syncthreads();
  if (t < HD) {
    s_hc[t] = h[i * HD + t];
  } else if (t < 192) {
    const int p = t - HD, a = p >> 3, b = p & 7;
    float s = 0.f;
#pragma unroll
    for (int d = 0; d < 3; ++d) {
      const float dx = s_x[a * 3 + d] - s_x[b * 3 + d];
      s = fmaf(dx, dx, s);
    }
    s_hc[t] = s;
  }
  __syncthreads();
  float p = 0.f, q = 0.f;
  for (int k = 0; k < 192; ++k) {
    const float hv = s_hc[k];
    p = fmaf(hv, We0[(8 + k) * M + t], p);
    q = fmaf(hv, We0[(200 + k) * M + t], q);
  }
  P[i * M + t] = p;
  Q[i * M + t] = q + be0[t];                 // be0 folded
}

// ---------------------------------------------------------------------------
// Fused edge pipeline (R13 verbatim). Block = (i, 64-j tile), 4 waves;
// wave owns rows [16w,16w+16). acc[16] in AGPRs; B staged per-kt via
// global_load_lds; stage-0 on MFMA with spill-safe ordering.
// ---------------------------------------------------------------------------
__global__ __launch_bounds__(256, 3) void k_edge(
    const float* __restrict__ x,
    const float* __restrict__ P, const float* __restrict__ Q,
    const float* __restrict__ be1,
    const float* __restrict__ Winf, const float* __restrict__ binf,
    const float* __restrict__ bx0, const float* __restrict__ bx1,
    const float* __restrict__ bxo,
    const unsigned short* __restrict__ wsB,
    float* __restrict__ mi_acc, float* __restrict__ shift_acc)
{
  const int i  = blockIdx.x;
  const int j0 = blockIdx.y * JTILE;
  const int t  = threadIdx.x;
  const int lane = t & 63, wave = t >> 6;
  const int lnib = lane & 15, quad = lane >> 4;
  const int r0 = wave * RPW;       // block-local row base
  const int jw = j0 + r0;          // first edge (j) of this wave

  __shared__ __align__(16) unsigned short a_act[JTILE * PITCH];   // 33 KB
  __shared__ __align__(16) unsigned short B_buf[8192];            // 16 KB
  __shared__ __align__(16) float s_sqn[JTILE][8];                 // 2 KB
  __shared__ __align__(16) unsigned short s_sqnb[JTILE][8];       // 1 KB
  __shared__ float s_e[JTILE];                                    // 256 B

  // ---- sqn for this wave's 16 rows (fp32 for shift, bf16 for MFMA A) ----
#pragma unroll
  for (int kk = 0; kk < 2; ++kk) {
    const int idx = kk * 64 + lane;          // 0..127 = 16 rows x 8 heads
    const int r = idx >> 3, hh = idx & 7;
    const int j = jw + r;
    float s = 0.f;
#pragma unroll
    for (int d = 0; d < 3; ++d) {
      const float dx = x[j * 24 + hh * 3 + d] - x[i * 24 + hh * 3 + d];
      s = fmaf(dx, dx, s);
    }
    s_sqn[r0 + r][hh] = s;
    s_sqnb[r0 + r][hh] = f2bf(s);
  }

  const float binf0 = binf[0];

  f32x4 acc[16];                             // 64 floats -> AGPRs

  // ---- stage 0 via MFMA: acc init = P[j-row][col] (acc dead before this);
  //      A = sqn bf16 (k>=8 garbage, B frag rows zero); epilogue adds Q'[i] ----
  {
#pragma unroll
    for (int nt = 0; nt < 16; ++nt)
#pragma unroll
      for (int reg = 0; reg < 4; ++reg)
        acc[nt][reg] = P[(jw + quad * 4 + reg) * M + nt * 16 + lnib];
    const v8bf aS = *(const v8bf*)&s_sqnb[r0 + lnib][0];
    const unsigned short* B0 = wsB + 200704;
#pragma unroll
    for (int nt = 0; nt < 16; ++nt) {
      const v8bf bv = *(const v8bf*)&B0[(nt * 64 + lane) * 8];
      acc[nt] = __builtin_amdgcn_mfma_f32_16x16x32_bf16(aS, bv, acc[nt], 0, 0, 0);
    }
#pragma unroll
    for (int nt = 0; nt < 16; ++nt) {
      const float qv = Q[i * M + nt * 16 + lnib];
#pragma unroll
      for (int reg = 0; reg < 4; ++reg) {
        const int row = r0 + quad * 4 + reg;
        a_act[row * PITCH + nt * 16 + lnib] = f2bf_hi(silu_f(acc[nt][reg] + qv));
      }
    }
  }

  // Full 16-nt GEMM over this wave's 16 rows; B staged per-kt through LDS.
  auto run_gemm = [&](const unsigned short* __restrict__ Bg) {
#pragma unroll
    for (int kt = 0; kt < 8; ++kt) {
      __syncthreads();                       // all waves done with prior slice
      {
        const unsigned short* src = Bg + kt * 8192 + wave * 2048 + lane * 8;
        unsigned short* dst = &B_buf[wave * 2048];   // wave-uniform base
        gl2lds16(src,        dst);
        gl2lds16(src + 512,  dst + 512);
        gl2lds16(src + 1024, dst + 1024);
        gl2lds16(src + 1536, dst + 1536);
      }
      __syncthreads();                       // staging complete
      const v8bf a0 = *(const v8bf*)&a_act[(r0 + lnib) * PITCH + kt * 32 + quad * 8];
#pragma unroll
      for (int nt = 0; nt < 16; ++nt) {
        const v8bf bv = *(const v8bf*)&B_buf[nt * 512 + lane * 8];
        acc[nt] = __builtin_amdgcn_mfma_f32_16x16x32_bf16(a0, bv, acc[nt], 0, 0, 0);
      }
    }
  };

  // ===== GEMM1: m = silu(a1 @ We1 + be1), diag mask, gate =====
#pragma unroll
  for (int nt = 0; nt < 16; ++nt) {
    const float b = be1[nt * 16 + lnib];
    acc[nt] = (f32x4){b, b, b, b};
  }
  run_gemm(wsB);
  {
    float ge[4] = {0.f, 0.f, 0.f, 0.f};
#pragma unroll
    for (int nt = 0; nt < 16; ++nt) {
      const float wfv = Winf[nt * 16 + lnib];
#pragma unroll
      for (int reg = 0; reg < 4; ++reg) {
        float v = silu_f(acc[nt][reg]);
        const int row = r0 + quad * 4 + reg;
        if (j0 + row == i) v = 0.f;
        a_act[row * PITCH + nt * 16 + lnib] = f2bf_hi(v);
        ge[reg] = fmaf(v, wfv, ge[reg]);
      }
    }
#pragma unroll
    for (int reg = 0; reg < 4; ++reg) {
      float g = ge[reg];
      g += __shfl_xor(g, 1);
      g += __shfl_xor(g, 2);
      g += __shfl_xor(g, 4);
      g += __shfl_xor(g, 8);
      const float ev = sigmoid_f(g + binf0);
      if (lnib == 0) s_e[r0 + quad * 4 + reg] = ev;
    }
  }

  // ===== mi: wave-private LDS re-read of m, scaled by e[r] =====
  {
    const int c0 = lane * 4;
    f32x4 mip = (f32x4){0.f, 0.f, 0.f, 0.f};
#pragma unroll
    for (int r = 0; r < RPW; ++r) {
      const us4v mv = *(const us4v*)&a_act[(r0 + r) * PITCH + c0];
      const float ev = s_e[r0 + r];          // broadcast
      mip[0] = fmaf(bf2f(mv[0]), ev, mip[0]);
      mip[1] = fmaf(bf2f(mv[1]), ev, mip[1]);
      mip[2] = fmaf(bf2f(mv[2]), ev, mip[2]);
      mip[3] = fmaf(bf2f(mv[3]), ev, mip[3]);
    }
    atomicAdd(&mi_acc[i * M + c0 + 0], mip[0]);
    atomicAdd(&mi_acc[i * M + c0 + 1], mip[1]);
    atomicAdd(&mi_acc[i * M + c0 + 2], mip[2]);
    atomicAdd(&mi_acc[i * M + c0 + 3], mip[3]);
  }

  // ===== GEMM2: a2 = silu(m @ Wx0 + bx0) =====
#pragma unroll
  for (int nt = 0; nt < 16; ++nt) {
    const float b = bx0[nt * 16 + lnib];
    acc[nt] = (f32x4){b, b, b, b};
  }
  run_gemm(wsB + 65536);
#pragma unroll
  for (int nt = 0; nt < 16; ++nt)
#pragma unroll
    for (int reg = 0; reg < 4; ++reg) {
      const int row = r0 + quad * 4 + reg;
      a_act[row * PITCH + nt * 16 + lnib] = f2bf_hi(silu_f(acc[nt][reg]));
    }

  // ===== GEMM3: a3 = silu(a2 @ Wx1 + bx1) =====
#pragma unroll
  for (int nt = 0; nt < 16; ++nt) {
    const float b = bx1[nt * 16 + lnib];
    acc[nt] = (f32x4){b, b, b, b};
  }
  run_gemm(wsB + 131072);
#pragma unroll
  for (int nt = 0; nt < 16; ++nt)
#pragma unroll
    for (int reg = 0; reg < 4; ++reg) {
      const int row = r0 + quad * 4 + reg;
      a_act[row * PITCH + nt * 16 + lnib] = f2bf_hi(silu_f(acc[nt][reg]));
    }

  // ===== GEMM4: px = a3 @ Wxo + bxo (N padded to 16; cols 8..15 zero) =====
  f32x4 px;
  {
    const float b = (lnib < 8) ? bxo[lnib] : 0.f;
    px = (f32x4){b, b, b, b};
    const unsigned short* B = wsB + 196608;
#pragma unroll
    for (int kt = 0; kt < 8; ++kt) {
      const v8bf a0 = *(const v8bf*)&a_act[(r0 + lnib) * PITCH + kt * 32 + quad * 8];
      const v8bf bv = *(const v8bf*)&B[(kt * 64 + lane) * 8];
      px = __builtin_amdgcn_mfma_f32_16x16x32_bf16(a0, bv, px, 0, 0, 0);
    }
  }

  // ===== shift: per-head normalized coordinate aggregation (wave-local) =====
  {
    const int hh = lnib & 7;   // lanes lnib>=8 hold zero px (padded B cols)
    const float xi0 = x[i * 24 + hh * 3 + 0];
    const float xi1 = x[i * 24 + hh * 3 + 1];
    const float xi2 = x[i * 24 + hh * 3 + 2];
    float p0 = 0.f, p1 = 0.f, p2 = 0.f;
#pragma unroll
    for (int reg = 0; reg < 4; ++reg) {
      const int row = r0 + quad * 4 + reg;
      const int jg = j0 + row;
      if (jg != i) {
        const float pxv = px[reg];
        const float sq  = s_sqn[row][hh];
        const float f   = pxv * __builtin_amdgcn_rcpf(sqrtf(sq + 1e-8f) + 1.f);
        p0 = fmaf(x[jg * 24 + hh * 3 + 0] - xi0, f, p0);
        p1 = fmaf(x[jg * 24 + hh * 3 + 1] - xi1, f, p1);
        p2 = fmaf(x[jg * 24 + hh * 3 + 2] - xi2, f, p2);
      }
    }
    p0 += __shfl_xor(p0, 16); p0 += __shfl_xor(p0, 32);
    p1 += __shfl_xor(p1, 16); p1 += __shfl_xor(p1, 32);
    p2 += __shfl_xor(p2, 16); p2 += __shfl_xor(p2, 32);
    if (lane < 8) {
      atomicAdd(&shift_acc[i * 24 + hh * 3 + 0], p0);
      atomicAdd(&shift_acc[i * 24 + hh * 3 + 1], p1);
      atomicAdd(&shift_acc[i * 24 + hh * 3 + 2], p2);
    }
  }
}

// ---------------------------------------------------------------------------
// h-output (phi_h MLP + residual) with x-output folded in (threads t<24).
// ---------------------------------------------------------------------------
__global__ __launch_bounds__(256) void k_hout(
    const float* __restrict__ x, const float* __restrict__ shift,
    const float* __restrict__ h, const float* __restrict__ mi,
    const float* __restrict__ Wh0, const float* __restrict__ bh0,
    const float* __restrict__ Wh1, const float* __restrict__ bh1,
    const float* __restrict__ Who, const float* __restrict__ bho,
    float* __restrict__ out_x, float* __restrict__ out_h)
{
  const int i = blockIdx.x, t = threadIdx.x;
  __shared__ float s_in[M + HD];
  __shared__ float s_b[M];
  if (t < 24) out_x[i * 24 + t] = x[i * 24 + t] + shift[i * 24 + t] * (1.f / 511.f);
  s_in[t] = mi[i * M + t];
  if (t < HD) s_in[M + t] = h[i * HD + t];
  __syncthreads();
  float acc = bh0[t];
  for (int k = 0; k < M + HD; ++k) acc = fmaf(s_in[k], Wh0[k * M + t], acc);
  s_b[t] = silu_f(acc);
  __syncthreads();
  float acc2 = bh1[t];
  for (int k = 0; k < M; ++k) acc2 = fmaf(s_b[k], Wh1[k * M + t], acc2);
  const float a1v = silu_f(acc2);
  __syncthreads();
  s_in[t] = a1v;
  __syncthreads();
  if (t < HD) {
    float o = bho[t];
    for (int k = 0; k < M; ++k) o = fmaf(s_in[k], Who[k * HD + t], o);
    out_h[i * HD + t] = h[i * HD + t] + o;
  }
}

// ---------------------------------------------------------------------------
extern "C" void kernel_launch(void* const* d_in, const int* in_sizes, int n_in,
                              void* d_out, int out_size, void* d_ws, size_t ws_size,
                              hipStream_t stream)
{
  const float* x    = (const float*)d_in[0];
  const float* h    = (const float*)d_in[1];
  const float* We0  = (const float*)d_in[2];
  const float* be0  = (const float*)d_in[3];
  const float* We1  = (const float*)d_in[4];
  const float* be1  = (const float*)d_in[5];
  const float* Winf = (const float*)d_in[6];
  const float* binf = (const float*)d_in[7];
  const float* Wx0  = (const float*)d_in[8];
  const float* bx0  = (const float*)d_in[9];
  const float* Wx1  = (const float*)d_in[10];
  const float* bx1  = (const float*)d_in[11];
  const float* Wxo  = (const float*)d_in[12];
  const float* bxo  = (const float*)d_in[13];
  const float* Wh0  = (const float*)d_in[14];
  const float* bh0  = (const float*)d_in[15];
  const float* Wh1  = (const float*)d_in[16];
  const float* bh1  = (const float*)d_in[17];
  const float* Who  = (const float*)d_in[18];
  const float* bho  = (const float*)d_in[19];

  float* out_x = (float*)d_out;                 // [512,8,3]
  float* out_h = out_x + N_NODES * NH * 3;      // [512,128]

  // ws layout (float units): mi[131072] | shift[12288] | P[131072] | Q[131072] | wsB(bf16)
  float* ws    = (float*)d_ws;
  float* mi    = ws;
  float* shift = ws + 131072;
  float* P     = ws + 143360;
  float* Q     = ws + 274432;
  unsigned short* wsB = (unsigned short*)(ws + 405504);

  k_pre<<<816 + N_NODES, 256, 0, stream>>>(
      x, h, We0, be0, We1, Wx0, Wx1, Wxo, wsB, P, Q, mi, shift);
  k_edge<<<dim3(N_NODES, N_NODES / JTILE), 256, 0, stream>>>(
      x, P, Q, be1, Winf, binf, bx0, bx1, bxo, wsB, mi, shift);
  k_hout<<<N_NODES, 256, 0, stream>>>(
      x, shift, h, mi, Wh0, bh0, Wh1, bh1, Who, bho, out_x, out_h);
}

// Round 20
// 306.338 us; speedup vs baseline: 1.0597x; 1.0344x over previous
//
#include <hip/hip_runtime.h>
#include <math.h>

// EGCL_Multi on MFMA. Best measured configuration (R17, 306.7 us):
// 512-thr k_edge (8 waves = 4 row-groups x 2 col-halves, acc[8]) with
// double-buffered B staging (1 barrier/kt) + coalesced weight-prep.
// N=512, NH=8, HD=128, M=256.
#define N_NODES 512
#define NH 8
#define HD 128
#define M 256
#define PITCH 264        // LDS activation row pitch in bf16 (528B)
#define JTILE 64         // edges (j) per block = 4 row-groups x 16
#define RPW 16           // rows per row-group

typedef __bf16 v8bf __attribute__((ext_vector_type(8)));
typedef float f32x4 __attribute__((ext_vector_type(4)));
typedef unsigned short us4v __attribute__((ext_vector_type(4)));

__device__ __forceinline__ float silu_f(float v) {
  return v * __builtin_amdgcn_rcpf(1.f + __expf(-v));
}
__device__ __forceinline__ float sigmoid_f(float v) {
  return __builtin_amdgcn_rcpf(1.f + __expf(-v));
}
// RNE (weight prep only)
__device__ __forceinline__ unsigned short f2bf(float f) {
  unsigned u = __float_as_uint(f);
  u += 0x7fffu + ((u >> 16) & 1u);
  return (unsigned short)(u >> 16);
}
// cheap half-up rounding (epilogue stores)
__device__ __forceinline__ unsigned short f2bf_hi(float f) {
  return (unsigned short)((__float_as_uint(f) + 0x8000u) >> 16);
}
__device__ __forceinline__ float bf2f(unsigned short s) {
  return __uint_as_float(((unsigned)s) << 16);
}

// async global->LDS, 16B/lane; LDS dest = wave-uniform base + lane*16.
__device__ __forceinline__ void gl2lds16(const unsigned short* g, unsigned short* l) {
  __builtin_amdgcn_global_load_lds(
      (const __attribute__((address_space(1))) unsigned int*)g,
      (__attribute__((address_space(3))) unsigned int*)l, 16, 0, 0);
}

// ---------------------------------------------------------------------------
// Fused prep (blocks 0..815, COALESCED source reads) + P/Q & zeroing (816..).
// Frag layout: frag[((kt*16+nt)*64+lane)*8+j] = W[kt*32+(lane>>4)*8+j][nt*16+(lane&15)]
// We1 @0, Wx0 @65536, Wx1 @131072, Wxo(256x8 pad16) @196608,
// We0[0:8] (K=8 pad 32, 16 nt tiles) @200704 (8192 shorts).
// ---------------------------------------------------------------------------
__global__ __launch_bounds__(256) void k_pre(
    const float* __restrict__ x, const float* __restrict__ h,
    const float* __restrict__ We0, const float* __restrict__ be0,
    const float* __restrict__ We1, const float* __restrict__ Wx0,
    const float* __restrict__ Wx1, const float* __restrict__ Wxo,
    unsigned short* __restrict__ wsB,
    float* __restrict__ P, float* __restrict__ Q,
    float* __restrict__ mi, float* __restrict__ shift)
{
  const int t = threadIdx.x;
  if (blockIdx.x < 816) {
    const int gid = blockIdx.x * 256 + t;
    if (gid >= 208896) return;
    float val;
    int dst;
    if (gid < 196608) {                      // We1/Wx0/Wx1: e = k*256+n (coalesced)
      const int layer = gid >> 16, e = gid & 65535;
      const int k = e >> 8, n = e & 255;
      const float* W = (layer == 0) ? We1 : (layer == 1) ? Wx0 : Wx1;
      val = W[e];
      const int kt = k >> 5, w = k & 31, quad = w >> 3, j = w & 7;
      const int nt = n >> 4, lnib = n & 15;
      dst = layer * 65536 + ((kt * 16 + nt) * 64 + quad * 16 + lnib) * 8 + j;
    } else if (gid < 198656) {               // Wxo valid: e = k*8+col (coalesced)
      const int e = gid - 196608;
      val = Wxo[e];
      const int k = e >> 3, col = e & 7;
      const int kt = k >> 5, w = k & 31, quad = w >> 3, j = w & 7;
      dst = 196608 + (kt * 64 + quad * 16 + col) * 8 + j;
    } else if (gid < 200704) {               // Wxo pad (cols 8..15) = 0
      const int e = gid - 198656;
      val = 0.f;
      const int k = e >> 3, col = e & 7;
      const int kt = k >> 5, w = k & 31, quad = w >> 3, j = w & 7;
      dst = 196608 + (kt * 64 + quad * 16 + col + 8) * 8 + j;
    } else if (gid < 202752) {               // We0[0:8] valid: e = j*256+n (coalesced)
      const int e = gid - 200704;
      val = We0[e];
      const int j = e >> 8, n = e & 255, nt = n >> 4, lnib = n & 15;
      dst = 200704 + (nt * 64 + lnib) * 8 + j;              // quad 0
    } else {                                 // We0 frag zero rows (quads 1..3)
      const int e = gid - 202752;
      val = 0.f;
      const int q = 1 + (e >> 11), rem = e & 2047;
      const int j = rem & 7, lnib = (rem >> 3) & 15, nt = rem >> 7;
      dst = 200704 + (nt * 64 + q * 16 + lnib) * 8 + j;
    }
    wsB[dst] = f2bf(val);
    return;
  }
  // ---- P/Q branch ----
  const int i = blockIdx.x - 816;
  __shared__ float s_x[24];
  __shared__ float s_hc[192];
  mi[i * M + t] = 0.f;                       // zeroing replaces memset
  if (t < 24) { shift[i * 24 + t] = 0.f; s_x[t] = x[i * 24 + t]; }
  __syncthreads();
  if (t < HD) {
    s_hc[t] = h[i * HD + t];
  } else if (t < 192) {
    const int p = t - HD, a = p >> 3, b = p & 7;
    float s = 0.f;
#pragma unroll
    for (int d = 0; d < 3; ++d) {
      const float dx = s_x[a * 3 + d] - s_x[b * 3 + d];
      s = fmaf(dx, dx, s);
    }
    s_hc[t] = s;
  }
  __syncthreads();
  float p = 0.f, q = 0.f;
  for (int k = 0; k < 192; ++k) {
    const float hv = s_hc[k];
    p = fmaf(hv, We0[(8 + k) * M + t], p);
    q = fmaf(hv, We0[(200 + k) * M + t], q);
  }
  P[i * M + t] = p;
  Q[i * M + t] = q + be0[t];                 // be0 folded
}

// ---------------------------------------------------------------------------
// Fused edge pipeline. Block = (i, 64-j tile), 512 threads = 8 waves.
// Wave w: row-group rg = w>>1 (rows [16rg,16rg+16)), col-half c = w&1.
// B double-buffered: stage kt+1 while MFMAing kt; 1 barrier per kt.
// ---------------------------------------------------------------------------
__global__ __launch_bounds__(512, 4) void k_edge(
    const float* __restrict__ x,
    const float* __restrict__ P, const float* __restrict__ Q,
    const float* __restrict__ be1,
    const float* __restrict__ Winf, const float* __restrict__ binf,
    const float* __restrict__ bx0, const float* __restrict__ bx1,
    const float* __restrict__ bxo,
    const unsigned short* __restrict__ wsB,
    float* __restrict__ mi_acc, float* __restrict__ shift_acc)
{
  const int i  = blockIdx.x;
  const int j0 = blockIdx.y * JTILE;
  const int t  = threadIdx.x;
  const int lane = t & 63, wave = t >> 6;
  const int lnib = lane & 15, quad = lane >> 4;
  const int rg = wave >> 1, c = wave & 1;
  const int r0 = rg * RPW;
  const int jw = j0 + r0;
  const int cb = c * 128;

  __shared__ __align__(16) unsigned short a_act[JTILE * PITCH];   // 33 KB
  __shared__ __align__(16) unsigned short B_buf[2][8192];         // 32 KB (dbuf)
  __shared__ __align__(16) float s_sqn[JTILE][8];                 // 2 KB
  __shared__ __align__(16) unsigned short s_sqnb[JTILE][8];       // 1 KB
  __shared__ float s_red[JTILE][2];                               // 512 B
  __shared__ float s_e[JTILE];                                    // 256 B

  // one kt slice of B: wave stages 1024 shorts (2KB)
  auto stage = [&](const unsigned short* __restrict__ Bg, int kt, int which) {
    const unsigned short* src = Bg + kt * 8192 + wave * 1024 + lane * 8;
    unsigned short* dst = &B_buf[which][wave * 1024];   // wave-uniform base
    gl2lds16(src,       dst);
    gl2lds16(src + 512, dst + 512);
  };

  // ---- sqn (both c-waves write identical values — benign) ----
#pragma unroll
  for (int kk = 0; kk < 2; ++kk) {
    const int idx = kk * 64 + lane;
    const int r = idx >> 3, hh = idx & 7;
    const int j = jw + r;
    float s = 0.f;
#pragma unroll
    for (int d = 0; d < 3; ++d) {
      const float dx = x[j * 24 + hh * 3 + d] - x[i * 24 + hh * 3 + d];
      s = fmaf(dx, dx, s);
    }
    s_sqn[r0 + r][hh] = s;
    s_sqnb[r0 + r][hh] = f2bf(s);
  }

  // prefetch GEMM1 kt0 into buf0 (flies during stage-0; drained at run_gemm top)
  stage(wsB, 0, 0);

  const float binf0 = binf[0];

  f32x4 acc[8];                              // 32 floats -> AGPRs

  // ---- stage 0 via MFMA: acc init = P[j-row][col]; A = sqn bf16 (k>=8
  //      garbage, B frag rows zero); epilogue adds Q'[i] + silu -> a_act ----
  {
#pragma unroll
    for (int nt = 0; nt < 8; ++nt)
#pragma unroll
      for (int reg = 0; reg < 4; ++reg)
        acc[nt][reg] = P[(jw + quad * 4 + reg) * M + cb + nt * 16 + lnib];
    const v8bf aS = *(const v8bf*)&s_sqnb[r0 + lnib][0];
    const unsigned short* B0 = wsB + 200704;
#pragma unroll
    for (int nt = 0; nt < 8; ++nt) {
      const v8bf bv = *(const v8bf*)&B0[((c * 8 + nt) * 64 + lane) * 8];
      acc[nt] = __builtin_amdgcn_mfma_f32_16x16x32_bf16(aS, bv, acc[nt], 0, 0, 0);
    }
#pragma unroll
    for (int nt = 0; nt < 8; ++nt) {
      const float qv = Q[i * M + cb + nt * 16 + lnib];
#pragma unroll
      for (int reg = 0; reg < 4; ++reg) {
        const int row = r0 + quad * 4 + reg;
        a_act[row * PITCH + cb + nt * 16 + lnib] = f2bf_hi(silu_f(acc[nt][reg] + qv));
      }
    }
  }

  // Half-width GEMM (16 rows x 128 cols per wave), dbuf pipeline.
  // Precondition: Bg's kt0 slice already staged into buf0 (drained at top
  // barrier). Postcondition: Bnext's kt0 staged into buf0 + drained.
  auto run_gemm = [&](const unsigned short* __restrict__ Bg,
                      const unsigned short* __restrict__ Bnext) {
    __syncthreads();   // prior epilogue visible + pending staging drained
#pragma unroll
    for (int kt = 0; kt < 8; ++kt) {
      if (kt < 7)      stage(Bg, kt + 1, (kt + 1) & 1);
      else if (Bnext)  stage(Bnext, 0, 0);
      const v8bf a0 = *(const v8bf*)&a_act[(r0 + lnib) * PITCH + kt * 32 + quad * 8];
#pragma unroll
      for (int nt = 0; nt < 8; ++nt) {
        const v8bf bv = *(const v8bf*)&B_buf[kt & 1][(c * 8 + nt) * 512 + lane * 8];
        acc[nt] = __builtin_amdgcn_mfma_f32_16x16x32_bf16(a0, bv, acc[nt], 0, 0, 0);
      }
      __syncthreads(); // reads of buf[kt&1] done; staging issued above drained
    }
  };

  // ===== GEMM1: m = silu(a1 @ We1 + be1), diag mask, gate =====
#pragma unroll
  for (int nt = 0; nt < 8; ++nt) {
    const float b = be1[cb + nt * 16 + lnib];
    acc[nt] = (f32x4){b, b, b, b};
  }
  run_gemm(wsB, wsB + 65536);
  {
    float ge[4] = {0.f, 0.f, 0.f, 0.f};
#pragma unroll
    for (int nt = 0; nt < 8; ++nt) {
      const float wfv = Winf[cb + nt * 16 + lnib];
#pragma unroll
      for (int reg = 0; reg < 4; ++reg) {
        float v = silu_f(acc[nt][reg]);
        const int row = r0 + quad * 4 + reg;
        if (j0 + row == i) v = 0.f;
        a_act[row * PITCH + cb + nt * 16 + lnib] = f2bf_hi(v);
        ge[reg] = fmaf(v, wfv, ge[reg]);
      }
    }
#pragma unroll
    for (int reg = 0; reg < 4; ++reg) {
      float g = ge[reg];
      g += __shfl_xor(g, 1);
      g += __shfl_xor(g, 2);
      g += __shfl_xor(g, 4);
      g += __shfl_xor(g, 8);
      if (lnib == 0) s_red[r0 + quad * 4 + reg][c] = g;   // col-half partial
    }
  }
  __syncthreads();                           // m writes + gate partials visible
  if (t < JTILE) s_e[t] = sigmoid_f(s_red[t][0] + s_red[t][1] + binf0);
  __syncthreads();

  // ===== mi: re-read own (row-group, col-half) of m, scaled by e[row] =====
  {
    const int ch = cb + lane * 2;            // 2 channels per lane
    float m0 = 0.f, m1 = 0.f;
#pragma unroll
    for (int r = 0; r < RPW; ++r) {
      const unsigned mv = *(const unsigned*)&a_act[(r0 + r) * PITCH + ch];
      const float ev = s_e[r0 + r];
      m0 = fmaf(bf2f((unsigned short)(mv & 0xffffu)), ev, m0);
      m1 = fmaf(bf2f((unsigned short)(mv >> 16)), ev, m1);
    }
    atomicAdd(&mi_acc[i * M + ch + 0], m0);
    atomicAdd(&mi_acc[i * M + ch + 1], m1);
  }

  // ===== GEMM2: a2 = silu(m @ Wx0 + bx0) =====
#pragma unroll
  for (int nt = 0; nt < 8; ++nt) {
    const float b = bx0[cb + nt * 16 + lnib];
    acc[nt] = (f32x4){b, b, b, b};
  }
  run_gemm(wsB + 65536, wsB + 131072);
#pragma unroll
  for (int nt = 0; nt < 8; ++nt)
#pragma unroll
    for (int reg = 0; reg < 4; ++reg) {
      const int row = r0 + quad * 4 + reg;
      a_act[row * PITCH + cb + nt * 16 + lnib] = f2bf_hi(silu_f(acc[nt][reg]));
    }

  // ===== GEMM3: a3 = silu(a2 @ Wx1 + bx1) =====
#pragma unroll
  for (int nt = 0; nt < 8; ++nt) {
    const float b = bx1[cb + nt * 16 + lnib];
    acc[nt] = (f32x4){b, b, b, b};
  }
  run_gemm(wsB + 131072, nullptr);
#pragma unroll
  for (int nt = 0; nt < 8; ++nt)
#pragma unroll
    for (int reg = 0; reg < 4; ++reg) {
      const int row = r0 + quad * 4 + reg;
      a_act[row * PITCH + cb + nt * 16 + lnib] = f2bf_hi(silu_f(acc[nt][reg]));
    }
  __syncthreads();                           // a3 complete (GEMM4 reads all cols)

  // ===== GEMM4 + shift: c==0 waves only (one wave per row-group) =====
  if (c == 0) {
    f32x4 px;
    {
      const float b = (lnib < 8) ? bxo[lnib] : 0.f;
      px = (f32x4){b, b, b, b};
      const unsigned short* B = wsB + 196608;
#pragma unroll
      for (int kt = 0; kt < 8; ++kt) {
        const v8bf a0 = *(const v8bf*)&a_act[(r0 + lnib) * PITCH + kt * 32 + quad * 8];
        const v8bf bv = *(const v8bf*)&B[(kt * 64 + lane) * 8];
        px = __builtin_amdgcn_mfma_f32_16x16x32_bf16(a0, bv, px, 0, 0, 0);
      }
    }
    const int hh = lnib & 7;   // lanes lnib>=8 hold zero px (padded B cols)
    const float xi0 = x[i * 24 + hh * 3 + 0];
    const float xi1 = x[i * 24 + hh * 3 + 1];
    const float xi2 = x[i * 24 + hh * 3 + 2];
    float p0 = 0.f, p1 = 0.f, p2 = 0.f;
#pragma unroll
    for (int reg = 0; reg < 4; ++reg) {
      const int row = r0 + quad * 4 + reg;
      const int jg = j0 + row;
      if (jg != i) {
        const float pxv = px[reg];
        const float sq  = s_sqn[row][hh];
        const float f   = pxv * __builtin_amdgcn_rcpf(sqrtf(sq + 1e-8f) + 1.f);
        p0 = fmaf(x[jg * 24 + hh * 3 + 0] - xi0, f, p0);
        p1 = fmaf(x[jg * 24 + hh * 3 + 1] - xi1, f, p1);
        p2 = fmaf(x[jg * 24 + hh * 3 + 2] - xi2, f, p2);
      }
    }
    p0 += __shfl_xor(p0, 16); p0 += __shfl_xor(p0, 32);
    p1 += __shfl_xor(p1, 16); p1 += __shfl_xor(p1, 32);
    p2 += __shfl_xor(p2, 16); p2 += __shfl_xor(p2, 32);
    if (lane < 8) {
      atomicAdd(&shift_acc[i * 24 + hh * 3 + 0], p0);
      atomicAdd(&shift_acc[i * 24 + hh * 3 + 1], p1);
      atomicAdd(&shift_acc[i * 24 + hh * 3 + 2], p2);
    }
  }
}

// ---------------------------------------------------------------------------
// h-output (phi_h MLP + residual) with x-output folded in (threads t<24).
// ---------------------------------------------------------------------------
__global__ __launch_bounds__(256) void k_hout(
    const float* __restrict__ x, const float* __restrict__ shift,
    const float* __restrict__ h, const float* __restrict__ mi,
    const float* __restrict__ Wh0, const float* __restrict__ bh0,
    const float* __restrict__ Wh1, const float* __restrict__ bh1,
    const float* __restrict__ Who, const float* __restrict__ bho,
    float* __restrict__ out_x, float* __restrict__ out_h)
{
  const int i = blockIdx.x, t = threadIdx.x;
  __shared__ float s_in[M + HD];
  __shared__ float s_b[M];
  if (t < 24) out_x[i * 24 + t] = x[i * 24 + t] + shift[i * 24 + t] * (1.f / 511.f);
  s_in[t] = mi[i * M + t];
  if (t < HD) s_in[M + t] = h[i * HD + t];
  __syncthreads();
  float acc = bh0[t];
  for (int k = 0; k < M + HD; ++k) acc = fmaf(s_in[k], Wh0[k * M + t], acc);
  s_b[t] = silu_f(acc);
  __syncthreads();
  float acc2 = bh1[t];
  for (int k = 0; k < M; ++k) acc2 = fmaf(s_b[k], Wh1[k * M + t], acc2);
  const float a1v = silu_f(acc2);
  __syncthreads();
  s_in[t] = a1v;
  __syncthreads();
  if (t < HD) {
    float o = bho[t];
    for (int k = 0; k < M; ++k) o = fmaf(s_in[k], Who[k * HD + t], o);
    out_h[i * HD + t] = h[i * HD + t] + o;
  }
}

// ---------------------------------------------------------------------------
extern "C" void kernel_launch(void* const* d_in, const int* in_sizes, int n_in,
                              void* d_out, int out_size, void* d_ws, size_t ws_size,
                              hipStream_t stream)
{
  const float* x    = (const float*)d_in[0];
  const float* h    = (const float*)d_in[1];
  const float* We0  = (const float*)d_in[2];
  const float* be0  = (const float*)d_in[3];
  const float* We1  = (const float*)d_in[4];
  const float* be1  = (const float*)d_in[5];
  const float* Winf = (const float*)d_in[6];
  const float* binf = (const float*)d_in[7];
  const float* Wx0  = (const float*)d_in[8];
  const float* bx0  = (const float*)d_in[9];
  const float* Wx1  = (const float*)d_in[10];
  const float* bx1  = (const float*)d_in[11];
  const float* Wxo  = (const float*)d_in[12];
  const float* bxo  = (const float*)d_in[13];
  const float* Wh0  = (const float*)d_in[14];
  const float* bh0  = (const float*)d_in[15];
  const float* Wh1  = (const float*)d_in[16];
  const float* bh1  = (const float*)d_in[17];
  const float* Who  = (const float*)d_in[18];
  const float* bho  = (const float*)d_in[19];

  float* out_x = (float*)d_out;                 // [512,8,3]
  float* out_h = out_x + N_NODES * NH * 3;      // [512,128]

  // ws layout (float units): mi[131072] | shift[12288] | P[131072] | Q[131072] | wsB(bf16)
  float* ws    = (float*)d_ws;
  float* mi    = ws;
  float* shift = ws + 131072;
  float* P     = ws + 143360;
  float* Q     = ws + 274432;
  unsigned short* wsB = (unsigned short*)(ws + 405504);

  k_pre<<<816 + N_NODES, 256, 0, stream>>>(
      x, h, We0, be0, We1, Wx0, Wx1, Wxo, wsB, P, Q, mi, shift);
  k_edge<<<dim3(N_NODES, N_NODES / JTILE), 512, 0, stream>>>(
      x, P, Q, be1, Winf, binf, bx0, bx1, bxo, wsB, mi, shift);
  k_hout<<<N_NODES, 256, 0, stream>>>(
      x, shift, h, mi, Wh0, bh0, Wh1, bh1, Who, bho, out_x, out_h);
}